// Round 11
// baseline (429.547 us; speedup 1.0000x reference)
//
#include <hip/hip_runtime.h>
#include <math.h>

#define HDIM 64

typedef __attribute__((ext_vector_type(8))) short short8;
typedef __attribute__((ext_vector_type(4))) float floatx4;
typedef unsigned short ushort_t;

#define MFMA16(a, b, c) __builtin_amdgcn_mfma_f32_16x16x32_bf16(a, b, c, 0, 0, 0)

__device__ __forceinline__ ushort_t f2bf(float f) {
  union { float f; unsigned u; } v; v.f = f;
  unsigned u = v.u;
  return (ushort_t)((u + 0x7FFFu + ((u >> 16) & 1u)) >> 16);
}

__device__ __forceinline__ float silu1(float v) { return __fdividef(v, 1.0f + __expf(-v)); }
__device__ __forceinline__ float tanh1(float v) {
  float t = __expf(2.0f * v);
  return 1.0f - __fdividef(2.0f, t + 1.0f);
}

// ------------- fused prep: bf16 convert (x,pe) + receiver histogram/rank -------------
__global__ void kprep(const float* __restrict__ x, const float* __restrict__ pe,
                      ushort_t* __restrict__ d, int n,
                      const int* __restrict__ idx32, int* __restrict__ cnt,
                      int* __restrict__ erank, int E, int ncvtblk, int nhist) {
  int b = blockIdx.x;
  if (b < ncvtblk) {
    int i = (b * 256 + threadIdx.x) * 8;
    if (i < 2 * n) {
      const float* sp = (i < n) ? (x + i) : (pe + (i - n));
      float4 a = *(const float4*)sp;
      float4 bb = *(const float4*)(sp + 4);
      union { ushort_t u[8]; uint4 v; } r;
      r.u[0] = f2bf(a.x); r.u[1] = f2bf(a.y); r.u[2] = f2bf(a.z); r.u[3] = f2bf(a.w);
      r.u[4] = f2bf(bb.x); r.u[5] = f2bf(bb.y); r.u[6] = f2bf(bb.z); r.u[7] = f2bf(bb.w);
      *(uint4*)(d + i) = r.v;
    }
  } else {
    b -= ncvtblk;
    const int m = ((idx32[1] | idx32[3] | idx32[5] | idx32[7]) == 0) ? 2 : 1;
    for (int e = b * 256 + threadIdx.x; e < E; e += nhist * 256) {
      int r = idx32[(size_t)m * (E + e)];
      erank[e] = atomicAdd(&cnt[r], 1);
    }
  }
}

// parallel exclusive scan over cnt[0..n)
__global__ __launch_bounds__(256) void kscanA(const int* __restrict__ cnt,
                                              int* __restrict__ part, int n) {
  __shared__ int sm[256];
  int i = blockIdx.x * 256 + threadIdx.x;
  sm[threadIdx.x] = (i < n) ? cnt[i] : 0;
  __syncthreads();
  for (int d = 128; d > 0; d >>= 1) {
    if (threadIdx.x < d) sm[threadIdx.x] += sm[threadIdx.x + d];
    __syncthreads();
  }
  if (threadIdx.x == 0) part[blockIdx.x] = sm[0];
}

__global__ __launch_bounds__(1024) void kscanB(int* __restrict__ part, int nb) {
  __shared__ int sm[1024];
  int t = threadIdx.x;
  int v = (t < nb) ? part[t] : 0;
  sm[t] = v;
  __syncthreads();
  for (int d = 1; d < 1024; d <<= 1) {
    int w = (t >= d) ? sm[t - d] : 0;
    __syncthreads();
    sm[t] += w;
    __syncthreads();
  }
  if (t < nb) part[t] = sm[t] - v;   // exclusive base per chunk
}

__global__ __launch_bounds__(256) void kscanC(int* __restrict__ cnt,
                                              const int* __restrict__ part, int n) {
  __shared__ int sm[256];
  int i = blockIdx.x * 256 + threadIdx.x;
  int v = (i < n) ? cnt[i] : 0;
  sm[threadIdx.x] = v;
  __syncthreads();
  for (int d = 1; d < 256; d <<= 1) {
    int w = (threadIdx.x >= d) ? sm[threadIdx.x - d] : 0;
    __syncthreads();
    sm[threadIdx.x] += w;
    __syncthreads();
  }
  if (i < n) cnt[i] = part[blockIdx.x] + sm[threadIdx.x] - v;  // exclusive base
}

// scatter into sorted order: ONE packed 16B record per edge {s, r, dist, pad}.
// Single 16B scattered store halves partial-line RMW traffic vs split 8B+4B stores.
__global__ void kscatter(const int* __restrict__ idx32, const int* __restrict__ cnt,
                         const int* __restrict__ erank, const float* __restrict__ pos,
                         float4* __restrict__ erec, int E) {
  const int m = ((idx32[1] | idx32[3] | idx32[5] | idx32[7]) == 0) ? 2 : 1;
  for (int e = blockIdx.x * 256 + threadIdx.x; e < E; e += gridDim.x * 256) {
    int s = idx32[(size_t)m * e];
    int r = idx32[(size_t)m * (E + e)];
    int p = cnt[r] + erank[e];
    float dx = pos[3 * s + 0] - pos[3 * r + 0];
    float dy = pos[3 * s + 1] - pos[3 * r + 1];
    float dz = pos[3 * s + 2] - pos[3 * r + 2];
    erec[p] = make_float4(__int_as_float(s), __int_as_float(r),
                          sqrtf(dx * dx + dy * dy + dz * dz), 0.0f);
  }
}

// ================= merged edge kernel — R7/R10 body (measured 243-248 us) =================
// Compute body bit-identical to R10. Only the tile load changed: reads the packed erec
// record as int2 + float (same cache lines; once per 64-edge tile; negligible).
__global__ __launch_bounds__(256, 2) void kedge(
    const ushort_t* __restrict__ xb, const ushort_t* __restrict__ peb,
    const float4* __restrict__ erec,
    const float* __restrict__ mw1, const float* __restrict__ mb1,
    const float* __restrict__ mw2, const float* __restrict__ mb2,
    const float* __restrict__ pw1, const float* __restrict__ pb1,
    const float* __restrict__ pw2, const float* __restrict__ pb2,
    float* __restrict__ aggr, float* __restrict__ aggrp, int E) {
  __shared__ ushort_t w1m[16384];          // 32 KB  msg w1 rows 0..255, B-frag layout
  __shared__ ushort_t w1p[8192];           // 16 KB  pos w1 rows 0..127
  __shared__ ushort_t w2m[4096];           // 8 KB
  __shared__ ushort_t w2p[4096];           // 8 KB
  __shared__ ushort_t hmat[4][1152];       // 9.2 KB: per-wave 16x72 bf16 chunk
  __shared__ int   srow[4][64];
  __shared__ int   rrow[4][64];
  __shared__ float ddv[4][64];
  __shared__ float cb1m[64], cb2m[64], wdm[64];
  __shared__ float cb1p[64], cb2p[64], wdp[64];

  for (int i = threadIdx.x; i < 257 * 64; i += 256) {
    int k = i >> 6, n = i & 63; float v = mw1[i];
    if (k < 256) w1m[(((k >> 5) * 4 + ((k >> 3) & 3)) * 64 + n) * 8 + (k & 7)] = f2bf(v);
    else wdm[n] = v;                       // dist row stays fp32
  }
  for (int i = threadIdx.x; i < 129 * 64; i += 256) {
    int k = i >> 6, n = i & 63; float v = pw1[i];
    if (k < 128) w1p[(((k >> 5) * 4 + ((k >> 3) & 3)) * 64 + n) * 8 + (k & 7)] = f2bf(v);
    else wdp[n] = v;
  }
  for (int i = threadIdx.x; i < 64 * 64; i += 256) {
    int k = i >> 6, n = i & 63;
    int off = (((k >> 5) * 4 + ((k >> 3) & 3)) * 64 + n) * 8 + (k & 7);
    w2m[off] = f2bf(mw2[i]);
    w2p[off] = f2bf(pw2[i]);
  }
  if (threadIdx.x < 64) {
    cb1m[threadIdx.x] = mb1[threadIdx.x]; cb2m[threadIdx.x] = mb2[threadIdx.x];
    cb1p[threadIdx.x] = pb1[threadIdx.x]; cb2p[threadIdx.x] = pb2[threadIdx.x];
  }
  __syncthreads();

  const int lane = threadIdx.x & 63;
  const int wv   = threadIdx.x >> 6;
  const int n15  = lane & 15;
  const int quad = lane >> 4;
  const int gw = blockIdx.x * 4 + wv;
  ushort_t* hm = &hmat[wv][0];

  for (int base = gw * 64; base < E; base += gridDim.x * 256) {
    int r_lane;
    {
      int e = base + lane, ec = min(e, E - 1);
      const float4* rp = erec + ec;
      int2 sr = *(const int2*)rp;
      float dd = *((const float*)rp + 2);
      srow[wv][lane] = sr.x; rrow[wv][lane] = sr.y;
      r_lane = sr.y;
      ddv[wv][lane] = dd;
    }
    // segment-start mask for this 64-edge tile (one ballot; reused by both phases)
    unsigned long long bmask;
    {
      int rp = __shfl_up(r_lane, 1);
      bmask = __ballot((lane == 0) || (r_lane != rp));
    }
    int sm[4], rm[4];
#pragma unroll
    for (int mt = 0; mt < 4; ++mt) {
      sm[mt] = srow[wv][mt * 16 + n15];
      rm[mt] = rrow[wv][mt * 16 + n15];
    }

    // ===== fused layer-1 K-loop: acc (msg, K=257) and accp (pos, K=129) =====
    floatx4 acc[4][4], accp[4][4];
#pragma unroll
    for (int mt = 0; mt < 4; ++mt)
#pragma unroll
      for (int reg = 0; reg < 4; ++reg) {
        float dd = ddv[wv][mt * 16 + quad * 4 + reg];
#pragma unroll
        for (int nt = 0; nt < 4; ++nt) {
          acc[mt][nt][reg]  = cb1m[nt * 16 + n15] + dd * wdm[nt * 16 + n15];
          accp[mt][nt][reg] = cb1p[nt * 16 + n15] + dd * wdp[nt * 16 + n15];
        }
      }

#pragma unroll
    for (int ks = 0; ks < 8; ++ks) {
      const int seg = ks >> 1, half = ks & 1;
      const ushort_t* sb = (seg == 0 || seg == 2) ? xb : peb;
      const bool dopos = (seg & 1);              // segs 1 (pe_s) and 3 (pe_r) feed accp too
      const int  kp    = ((seg >> 1) << 1) | half;  // pos K-step index 0..3
      short8 B[4], Bp[4];
#pragma unroll
      for (int nt = 0; nt < 4; ++nt)
        B[nt] = *(const short8*)&w1m[((ks * 4 + quad) * 64 + nt * 16 + n15) * 8];
      if (dopos) {
#pragma unroll
        for (int nt = 0; nt < 4; ++nt)
          Bp[nt] = *(const short8*)&w1p[((kp * 4 + quad) * 64 + nt * 16 + n15) * 8];
      }
#pragma unroll
      for (int mt = 0; mt < 4; ++mt) {
        int row = (seg < 2) ? sm[mt] : rm[mt];
        short8 A = *(const short8*)(sb + (size_t)row * 64 + half * 32 + quad * 8);
#pragma unroll
        for (int nt = 0; nt < 4; ++nt)
          acc[mt][nt] = MFMA16(A, B[nt], acc[mt][nt]);
        if (dopos) {
#pragma unroll
          for (int nt = 0; nt < 4; ++nt)
            accp[mt][nt] = MFMA16(A, Bp[nt], accp[mt][nt]);
        }
      }
    }

    // ================= message epilogue (silu) =================
    {
      int pendR = -1; float pendV = 0.0f;
#pragma unroll
      for (int mt = 0; mt < 4; ++mt) {
#pragma unroll
        for (int nt = 0; nt < 4; ++nt)
#pragma unroll
          for (int reg = 0; reg < 4; ++reg)
            hm[(quad * 4 + reg) * 72 + nt * 16 + n15] = f2bf(silu1(acc[mt][nt][reg]));

        floatx4 o[4];
#pragma unroll
        for (int nt = 0; nt < 4; ++nt) {
          float bv = cb2m[nt * 16 + n15];
#pragma unroll
          for (int reg = 0; reg < 4; ++reg) o[nt][reg] = bv;
        }
#pragma unroll
        for (int ks = 0; ks < 2; ++ks) {
          short8 A = *(const short8*)&hm[n15 * 72 + ks * 32 + quad * 8];
          short8 B[4];
#pragma unroll
          for (int nt = 0; nt < 4; ++nt)
            B[nt] = *(const short8*)&w2m[((ks * 4 + quad) * 64 + nt * 16 + n15) * 8];
#pragma unroll
          for (int nt = 0; nt < 4; ++nt)
            o[nt] = MFMA16(A, B[nt], o[nt]);
        }

#pragma unroll
        for (int nt = 0; nt < 4; ++nt)
#pragma unroll
          for (int reg = 0; reg < 4; ++reg)
            o[nt][reg] = silu1(o[nt][reg]);

        // segmented reduction: register bit-walk over ballot mask (no LDS chain)
        int rem = E - (base + mt * 16);
        unsigned vmask = rem >= 16 ? 0xFFFFu : (rem <= 0 ? 0u : ((1u << rem) - 1u));
        unsigned m16 = ((unsigned)(bmask >> (mt * 16)) & 0xFFFFu) | 1u;
        int e0 = 0;
        while (e0 < 16) {
          unsigned above = m16 & ~((1u << (e0 + 1)) - 1u);
          int e1 = above ? __builtin_ctz(above) : 16;
          unsigned segm = (((e1 == 16) ? 0xFFFFu : ((1u << e1) - 1u)) & ~((1u << e0) - 1u)) & vmask;
          if (segm) {
            const int r0 = rrow[wv][mt * 16 + e0];
            float s0 = 0.0f, s1 = 0.0f, s2 = 0.0f, s3 = 0.0f;
#pragma unroll
            for (int reg = 0; reg < 4; ++reg) {
              float msk = (float)((segm >> (quad * 4 + reg)) & 1u);
              s0 = fmaf(msk, o[0][reg], s0);
              s1 = fmaf(msk, o[1][reg], s1);
              s2 = fmaf(msk, o[2][reg], s2);
              s3 = fmaf(msk, o[3][reg], s3);
            }
            s0 += __shfl_xor(s0, 16); s0 += __shfl_xor(s0, 32);
            s1 += __shfl_xor(s1, 16); s1 += __shfl_xor(s1, 32);
            s2 += __shfl_xor(s2, 16); s2 += __shfl_xor(s2, 32);
            s3 += __shfl_xor(s3, 16); s3 += __shfl_xor(s3, 32);
            float v = (quad & 2) ? ((quad & 1) ? s3 : s2) : ((quad & 1) ? s1 : s0);
            if (r0 != pendR) {
              if (pendR >= 0) unsafeAtomicAdd(aggr + (size_t)pendR * 64 + lane, pendV);
              pendR = r0; pendV = v;
            } else {
              pendV += v;
            }
          }
          e0 = e1;
        }
      }
      if (pendR >= 0) unsafeAtomicAdd(aggr + (size_t)pendR * 64 + lane, pendV);
    }

    // ================= positional epilogue (tanh) — layer-1 already in accp =================
    {
      int pendR = -1; float pendV = 0.0f;
#pragma unroll
      for (int mt = 0; mt < 4; ++mt) {
#pragma unroll
        for (int nt = 0; nt < 4; ++nt)
#pragma unroll
          for (int reg = 0; reg < 4; ++reg)
            hm[(quad * 4 + reg) * 72 + nt * 16 + n15] = f2bf(tanh1(accp[mt][nt][reg]));

        floatx4 o[4];
#pragma unroll
        for (int nt = 0; nt < 4; ++nt) {
          float bv = cb2p[nt * 16 + n15];
#pragma unroll
          for (int reg = 0; reg < 4; ++reg) o[nt][reg] = bv;
        }
#pragma unroll
        for (int ks = 0; ks < 2; ++ks) {
          short8 A = *(const short8*)&hm[n15 * 72 + ks * 32 + quad * 8];
          short8 B[4];
#pragma unroll
          for (int nt = 0; nt < 4; ++nt)
            B[nt] = *(const short8*)&w2p[((ks * 4 + quad) * 64 + nt * 16 + n15) * 8];
#pragma unroll
          for (int nt = 0; nt < 4; ++nt)
            o[nt] = MFMA16(A, B[nt], o[nt]);
        }

#pragma unroll
        for (int nt = 0; nt < 4; ++nt)
#pragma unroll
          for (int reg = 0; reg < 4; ++reg)
            o[nt][reg] = tanh1(o[nt][reg]);

        int rem = E - (base + mt * 16);
        unsigned vmask = rem >= 16 ? 0xFFFFu : (rem <= 0 ? 0u : ((1u << rem) - 1u));
        unsigned m16 = ((unsigned)(bmask >> (mt * 16)) & 0xFFFFu) | 1u;
        int e0 = 0;
        while (e0 < 16) {
          unsigned above = m16 & ~((1u << (e0 + 1)) - 1u);
          int e1 = above ? __builtin_ctz(above) : 16;
          unsigned segm = (((e1 == 16) ? 0xFFFFu : ((1u << e1) - 1u)) & ~((1u << e0) - 1u)) & vmask;
          if (segm) {
            const int r0 = rrow[wv][mt * 16 + e0];
            float s0 = 0.0f, s1 = 0.0f, s2 = 0.0f, s3 = 0.0f;
#pragma unroll
            for (int reg = 0; reg < 4; ++reg) {
              float msk = (float)((segm >> (quad * 4 + reg)) & 1u);
              s0 = fmaf(msk, o[0][reg], s0);
              s1 = fmaf(msk, o[1][reg], s1);
              s2 = fmaf(msk, o[2][reg], s2);
              s3 = fmaf(msk, o[3][reg], s3);
            }
            s0 += __shfl_xor(s0, 16); s0 += __shfl_xor(s0, 32);
            s1 += __shfl_xor(s1, 16); s1 += __shfl_xor(s1, 32);
            s2 += __shfl_xor(s2, 16); s2 += __shfl_xor(s2, 32);
            s3 += __shfl_xor(s3, 16); s3 += __shfl_xor(s3, 32);
            float v = (quad & 2) ? ((quad & 1) ? s3 : s2) : ((quad & 1) ? s1 : s0);
            if (r0 != pendR) {
              if (pendR >= 0) unsafeAtomicAdd(aggrp + (size_t)pendR * 64 + lane, pendV);
              pendR = r0; pendV = v;
            } else {
              pendV += v;
            }
          }
          e0 = e1;
        }
      }
      if (pendR >= 0) unsafeAtomicAdd(aggrp + (size_t)pendR * 64 + lane, pendV);
    }
  }
}

// ================= merged node kernel: blocks [0,nupd) do update MLP, rest do pe MLP =================
__global__ __launch_bounds__(256, 2) void knode(
    const ushort_t* __restrict__ xb, const ushort_t* __restrict__ peb,
    const float* aggr, const float* aggrp,
    const float* __restrict__ uw1, const float* __restrict__ ub1,
    const float* __restrict__ uw2, const float* __restrict__ ub2,
    const float* __restrict__ ew1, const float* __restrict__ eb1,
    const float* __restrict__ ew2, const float* __restrict__ eb2,
    float* out_upd, float* out_upe, int N, int nupd) {
  __shared__ ushort_t shraw[34816];        // 69.6 KB union: w1b | w2b | hmat
  __shared__ float cb1[64], cb2[64];

  const bool isupd = ((int)blockIdx.x < nupd);
  const int  K1    = isupd ? 192 : 128;
  ushort_t* w1b  = shraw;
  ushort_t* w2b  = shraw + (isupd ? 12288 : 8192);
  ushort_t* hmat = shraw + (isupd ? 16384 : 12288);  // 4 waves x 4608 ushort
  const float* w1 = isupd ? uw1 : ew1;
  const float* b1 = isupd ? ub1 : eb1;
  const float* w2 = isupd ? uw2 : ew2;
  const float* b2 = isupd ? ub2 : eb2;
  const float* ag = isupd ? aggr : aggrp;
  float* outp     = isupd ? out_upd : out_upe;

  for (int i = threadIdx.x * 4; i < K1 * 64; i += 1024) {
    float4 w = *(const float4*)&w1[i];
    int k = i >> 6, n = i & 63;
    int off = (((k >> 5) * 4 + ((k >> 3) & 3)) * 64 + n) * 8 + (k & 7);
    w1b[off] = f2bf(w.x); w1b[off + 8] = f2bf(w.y);
    w1b[off + 16] = f2bf(w.z); w1b[off + 24] = f2bf(w.w);
  }
  for (int i = threadIdx.x * 4; i < 64 * 64; i += 1024) {
    float4 w = *(const float4*)&w2[i];
    int k = i >> 6, n = i & 63;
    int off = (((k >> 5) * 4 + ((k >> 3) & 3)) * 64 + n) * 8 + (k & 7);
    w2b[off] = f2bf(w.x); w2b[off + 8] = f2bf(w.y);
    w2b[off + 16] = f2bf(w.z); w2b[off + 24] = f2bf(w.w);
  }
  if (threadIdx.x < 64) { cb1[threadIdx.x] = b1[threadIdx.x]; cb2[threadIdx.x] = b2[threadIdx.x]; }
  __syncthreads();

  const int lane = threadIdx.x & 63;
  const int wv   = threadIdx.x >> 6;
  const int n15  = lane & 15;
  const int quad = lane >> 4;
  const int bid  = isupd ? (int)blockIdx.x : ((int)blockIdx.x - nupd);
  const int nblk = isupd ? nupd : (gridDim.x - nupd);
  const int gw   = bid * 4 + wv;
  ushort_t* hm = hmat + wv * 4608;

  for (int base = gw * 64; base < N; base += nblk * 256) {
    floatx4 acc[4][4];
#pragma unroll
    for (int mt = 0; mt < 4; ++mt)
#pragma unroll
      for (int nt = 0; nt < 4; ++nt) {
        float bv = cb1[nt * 16 + n15];
#pragma unroll
        for (int reg = 0; reg < 4; ++reg) acc[mt][nt][reg] = bv;
      }

    // layer 1: K1 in steps of 32.
    const int nks = K1 >> 5;
    for (int ks = 0; ks < nks; ++ks) {
      const int seg = ks >> 1, half = ks & 1;
      const int lastseg = (nks >> 1) - 1;
      short8 B[4];
#pragma unroll
      for (int nt = 0; nt < 4; ++nt)
        B[nt] = *(const short8*)&w1b[((ks * 4 + quad) * 64 + nt * 16 + n15) * 8];
#pragma unroll
      for (int mt = 0; mt < 4; ++mt) {
        int row = min(base + mt * 16 + n15, N - 1);
        short8 A;
        if (seg == lastseg) {          // aggregated messages, fp32 -> bf16
          const float* ap = ag + (size_t)row * 64 + half * 32 + quad * 8;
          float4 f0 = *(const float4*)ap;
          float4 f1 = *(const float4*)(ap + 4);
          union { ushort_t u[8]; short8 s; } pk;
          pk.u[0] = f2bf(f0.x); pk.u[1] = f2bf(f0.y); pk.u[2] = f2bf(f0.z); pk.u[3] = f2bf(f0.w);
          pk.u[4] = f2bf(f1.x); pk.u[5] = f2bf(f1.y); pk.u[6] = f2bf(f1.z); pk.u[7] = f2bf(f1.w);
          A = pk.s;
        } else if (seg == 0 && isupd) {
          A = *(const short8*)(xb + (size_t)row * 64 + half * 32 + quad * 8);
        } else {
          A = *(const short8*)(peb + (size_t)row * 64 + half * 32 + quad * 8);
        }
#pragma unroll
        for (int nt = 0; nt < 4; ++nt)
          acc[mt][nt] = MFMA16(A, B[nt], acc[mt][nt]);
      }
    }

    // epilogue 1: act -> bf16 h-matrix (full 64x72)
#pragma unroll
    for (int mt = 0; mt < 4; ++mt)
#pragma unroll
      for (int nt = 0; nt < 4; ++nt)
#pragma unroll
        for (int reg = 0; reg < 4; ++reg) {
          float h = isupd ? silu1(acc[mt][nt][reg]) : tanh1(acc[mt][nt][reg]);
          hm[(mt * 16 + quad * 4 + reg) * 72 + nt * 16 + n15] = f2bf(h);
        }

    // layer 2: K=64 in 2 steps
    floatx4 o[4][4];
#pragma unroll
    for (int mt = 0; mt < 4; ++mt)
#pragma unroll
      for (int nt = 0; nt < 4; ++nt) {
        float bv = cb2[nt * 16 + n15];
#pragma unroll
        for (int reg = 0; reg < 4; ++reg) o[mt][nt][reg] = bv;
      }
#pragma unroll
    for (int ks = 0; ks < 2; ++ks) {
      short8 B[4];
#pragma unroll
      for (int nt = 0; nt < 4; ++nt)
        B[nt] = *(const short8*)&w2b[((ks * 4 + quad) * 64 + nt * 16 + n15) * 8];
#pragma unroll
      for (int mt = 0; mt < 4; ++mt) {
        short8 A = *(const short8*)&hm[(mt * 16 + n15) * 72 + ks * 32 + quad * 8];
#pragma unroll
        for (int nt = 0; nt < 4; ++nt)
          o[mt][nt] = MFMA16(A, B[nt], o[mt][nt]);
      }
    }

#pragma unroll
    for (int mt = 0; mt < 4; ++mt)
#pragma unroll
      for (int reg = 0; reg < 4; ++reg) {
        const int row = base + mt * 16 + quad * 4 + reg;
        if (row < N) {
#pragma unroll
          for (int nt = 0; nt < 4; ++nt) {
            float v = o[mt][nt][reg];
            outp[(size_t)row * 64 + nt * 16 + n15] = isupd ? v : tanh1(v);
          }
        }
      }
  }
}

extern "C" void kernel_launch(void* const* d_in, const int* in_sizes, int n_in,
                              void* d_out, int out_size, void* d_ws, size_t ws_size,
                              hipStream_t stream) {
  const float* x    = (const float*)d_in[0];
  const float* pos  = (const float*)d_in[1];
  const float* pe   = (const float*)d_in[2];
  const int*   eidx = (const int*)d_in[3];
  const float* msg_w1  = (const float*)d_in[4];
  const float* msg_b1  = (const float*)d_in[5];
  const float* msg_w2  = (const float*)d_in[6];
  const float* msg_b2  = (const float*)d_in[7];
  const float* mpos_w1 = (const float*)d_in[8];
  const float* mpos_b1 = (const float*)d_in[9];
  const float* mpos_w2 = (const float*)d_in[10];
  const float* mpos_b2 = (const float*)d_in[11];
  const float* upd_w1  = (const float*)d_in[12];
  const float* upd_b1  = (const float*)d_in[13];
  const float* upd_w2  = (const float*)d_in[14];
  const float* upd_b2  = (const float*)d_in[15];
  const float* upe_w1  = (const float*)d_in[16];
  const float* upe_b1  = (const float*)d_in[17];
  const float* upe_w2  = (const float*)d_in[18];
  const float* upe_b2  = (const float*)d_in[19];

  const int N = in_sizes[0] / HDIM;
  const int E = in_sizes[3] / 2;

  float* out_upd = (float*)d_out;                 // aggr accumulator, then update out
  float* out_upe = out_upd + (size_t)N * HDIM;    // aggr_pos accumulator, then update_pe out

  // workspace layout: xb | peb | cnt[N] pad[4] | erec[E] (16B-aligned) | part | erank
  ushort_t* xb    = (ushort_t*)d_ws;
  ushort_t* peb   = xb + (size_t)N * HDIM;
  int*      cnt   = (int*)(peb + (size_t)N * HDIM);
  int*      pad4  = cnt + N;
  float4*   erec  = (float4*)(pad4 + 4);
  int*      part  = (int*)(erec + E);
  int*      erank = part + 1024;

  hipMemsetAsync(d_out, 0, (size_t)2 * N * HDIM * sizeof(float), stream);
  hipMemsetAsync(cnt, 0, (size_t)N * sizeof(int), stream);

  const int ncv = N * HDIM;
  const int ncvtblk = (2 * ncv / 8 + 255) / 256;
  const int nhist = 2048;
  kprep<<<ncvtblk + nhist, 256, 0, stream>>>(x, pe, xb, ncv, eidx, cnt, erank, E,
                                             ncvtblk, nhist);

  const int nb = (N + 255) / 256;
  kscanA<<<nb, 256, 0, stream>>>(cnt, part, N);
  kscanB<<<1, 1024, 0, stream>>>(part, nb);
  kscanC<<<nb, 256, 0, stream>>>(cnt, part, N);
  kscatter<<<2048, 256, 0, stream>>>(eidx, cnt, erank, pos, erec, E);

  kedge<<<512, 256, 0, stream>>>(xb, peb, erec,
                                 msg_w1, msg_b1, msg_w2, msg_b2,
                                 mpos_w1, mpos_b1, mpos_w2, mpos_b2,
                                 out_upd, out_upe, E);

  // merged node kernel: both MLPs in one dispatch
  const int ntiles = (N + 63) / 64;
  const int nupd   = (ntiles + 3) / 4;
  knode<<<2 * nupd, 256, 0, stream>>>(xb, peb, out_upd, out_upe,
                                      upd_w1, upd_b1, upd_w2, upd_b2,
                                      upe_w1, upe_b1, upe_w2, upe_b2,
                                      out_upd, out_upe, N, nupd);
}

// Round 12
// 427.490 us; speedup vs baseline: 1.0048x; 1.0048x over previous
//
#include <hip/hip_runtime.h>
#include <math.h>

#define HDIM 64

typedef __attribute__((ext_vector_type(8))) short short8;
typedef __attribute__((ext_vector_type(4))) float floatx4;
typedef unsigned short ushort_t;

#define MFMA16(a, b, c) __builtin_amdgcn_mfma_f32_16x16x32_bf16(a, b, c, 0, 0, 0)

__device__ __forceinline__ ushort_t f2bf(float f) {
  union { float f; unsigned u; } v; v.f = f;
  unsigned u = v.u;
  return (ushort_t)((u + 0x7FFFu + ((u >> 16) & 1u)) >> 16);
}

// packed f32x2 -> bf16x2 (RNE, single VALU inst; same rounding as f2bf)
__device__ __forceinline__ unsigned cvtpk_bf16(float lo, float hi) {
  unsigned r;
  asm("v_cvt_pk_bf16_f32 %0, %1, %2" : "=v"(r) : "v"(lo), "v"(hi));
  return r;
}

__device__ __forceinline__ float silu1(float v) { return __fdividef(v, 1.0f + __expf(-v)); }
__device__ __forceinline__ float tanh1(float v) {
  float t = __expf(2.0f * v);
  return 1.0f - __fdividef(2.0f, t + 1.0f);
}

// ------------- fused prep: bf16 convert (x,pe) + receiver histogram/rank -------------
__global__ void kprep(const float* __restrict__ x, const float* __restrict__ pe,
                      ushort_t* __restrict__ d, int n,
                      const int* __restrict__ idx32, int* __restrict__ cnt,
                      int* __restrict__ erank, int E, int ncvtblk, int nhist) {
  int b = blockIdx.x;
  if (b < ncvtblk) {
    int i = (b * 256 + threadIdx.x) * 8;
    if (i < 2 * n) {
      const float* sp = (i < n) ? (x + i) : (pe + (i - n));
      float4 a = *(const float4*)sp;
      float4 bb = *(const float4*)(sp + 4);
      union { ushort_t u[8]; uint4 v; } r;
      r.u[0] = f2bf(a.x); r.u[1] = f2bf(a.y); r.u[2] = f2bf(a.z); r.u[3] = f2bf(a.w);
      r.u[4] = f2bf(bb.x); r.u[5] = f2bf(bb.y); r.u[6] = f2bf(bb.z); r.u[7] = f2bf(bb.w);
      *(uint4*)(d + i) = r.v;
    }
  } else {
    b -= ncvtblk;
    const int m = ((idx32[1] | idx32[3] | idx32[5] | idx32[7]) == 0) ? 2 : 1;
    for (int e = b * 256 + threadIdx.x; e < E; e += nhist * 256) {
      int r = idx32[(size_t)m * (E + e)];
      erank[e] = atomicAdd(&cnt[r], 1);
    }
  }
}

// parallel exclusive scan over cnt[0..n)
__global__ __launch_bounds__(256) void kscanA(const int* __restrict__ cnt,
                                              int* __restrict__ part, int n) {
  __shared__ int sm[256];
  int i = blockIdx.x * 256 + threadIdx.x;
  sm[threadIdx.x] = (i < n) ? cnt[i] : 0;
  __syncthreads();
  for (int d = 128; d > 0; d >>= 1) {
    if (threadIdx.x < d) sm[threadIdx.x] += sm[threadIdx.x + d];
    __syncthreads();
  }
  if (threadIdx.x == 0) part[blockIdx.x] = sm[0];
}

__global__ __launch_bounds__(1024) void kscanB(int* __restrict__ part, int nb) {
  __shared__ int sm[1024];
  int t = threadIdx.x;
  int v = (t < nb) ? part[t] : 0;
  sm[t] = v;
  __syncthreads();
  for (int d = 1; d < 1024; d <<= 1) {
    int w = (t >= d) ? sm[t - d] : 0;
    __syncthreads();
    sm[t] += w;
    __syncthreads();
  }
  if (t < nb) part[t] = sm[t] - v;   // exclusive base per chunk
}

__global__ __launch_bounds__(256) void kscanC(int* __restrict__ cnt,
                                              const int* __restrict__ part, int n) {
  __shared__ int sm[256];
  int i = blockIdx.x * 256 + threadIdx.x;
  int v = (i < n) ? cnt[i] : 0;
  sm[threadIdx.x] = v;
  __syncthreads();
  for (int d = 1; d < 256; d <<= 1) {
    int w = (threadIdx.x >= d) ? sm[threadIdx.x - d] : 0;
    __syncthreads();
    sm[threadIdx.x] += w;
    __syncthreads();
  }
  if (i < n) cnt[i] = part[blockIdx.x] + sm[threadIdx.x] - v;  // exclusive base
}

// scatter into sorted order: ONE packed 16B record per edge {s, r, dist, pad}.
__global__ void kscatter(const int* __restrict__ idx32, const int* __restrict__ cnt,
                         const int* __restrict__ erank, const float* __restrict__ pos,
                         float4* __restrict__ erec, int E) {
  const int m = ((idx32[1] | idx32[3] | idx32[5] | idx32[7]) == 0) ? 2 : 1;
  for (int e = blockIdx.x * 256 + threadIdx.x; e < E; e += gridDim.x * 256) {
    int s = idx32[(size_t)m * e];
    int r = idx32[(size_t)m * (E + e)];
    int p = cnt[r] + erank[e];
    float dx = pos[3 * s + 0] - pos[3 * r + 0];
    float dy = pos[3 * s + 1] - pos[3 * r + 1];
    float dz = pos[3 * s + 2] - pos[3 * r + 2];
    erec[p] = make_float4(__int_as_float(s), __int_as_float(r),
                          sqrtf(dx * dx + dy * dy + dz * dz), 0.0f);
  }
}

// ================= merged edge kernel — R10 body + cvt_pk h-conversion =================
// Only change vs R10/R11 (247us stable): the h-matrix bf16 conversion uses
// v_cvt_pk_bf16_f32 (1 inst / 2 values) instead of manual f2bf (~4-5 insts/value).
// 128 conversions/thread/iter -> ~400-500 fewer VALU insts/iter. Register-neutral.
__global__ __launch_bounds__(256, 2) void kedge(
    const ushort_t* __restrict__ xb, const ushort_t* __restrict__ peb,
    const float4* __restrict__ erec,
    const float* __restrict__ mw1, const float* __restrict__ mb1,
    const float* __restrict__ mw2, const float* __restrict__ mb2,
    const float* __restrict__ pw1, const float* __restrict__ pb1,
    const float* __restrict__ pw2, const float* __restrict__ pb2,
    float* __restrict__ aggr, float* __restrict__ aggrp, int E) {
  __shared__ ushort_t w1m[16384];          // 32 KB  msg w1 rows 0..255, B-frag layout
  __shared__ ushort_t w1p[8192];           // 16 KB  pos w1 rows 0..127
  __shared__ ushort_t w2m[4096];           // 8 KB
  __shared__ ushort_t w2p[4096];           // 8 KB
  __shared__ ushort_t hmat[4][1152];       // 9.2 KB: per-wave 16x72 bf16 chunk
  __shared__ int   srow[4][64];
  __shared__ int   rrow[4][64];
  __shared__ float ddv[4][64];
  __shared__ float cb1m[64], cb2m[64], wdm[64];
  __shared__ float cb1p[64], cb2p[64], wdp[64];

  for (int i = threadIdx.x; i < 257 * 64; i += 256) {
    int k = i >> 6, n = i & 63; float v = mw1[i];
    if (k < 256) w1m[(((k >> 5) * 4 + ((k >> 3) & 3)) * 64 + n) * 8 + (k & 7)] = f2bf(v);
    else wdm[n] = v;                       // dist row stays fp32
  }
  for (int i = threadIdx.x; i < 129 * 64; i += 256) {
    int k = i >> 6, n = i & 63; float v = pw1[i];
    if (k < 128) w1p[(((k >> 5) * 4 + ((k >> 3) & 3)) * 64 + n) * 8 + (k & 7)] = f2bf(v);
    else wdp[n] = v;
  }
  for (int i = threadIdx.x; i < 64 * 64; i += 256) {
    int k = i >> 6, n = i & 63;
    int off = (((k >> 5) * 4 + ((k >> 3) & 3)) * 64 + n) * 8 + (k & 7);
    w2m[off] = f2bf(mw2[i]);
    w2p[off] = f2bf(pw2[i]);
  }
  if (threadIdx.x < 64) {
    cb1m[threadIdx.x] = mb1[threadIdx.x]; cb2m[threadIdx.x] = mb2[threadIdx.x];
    cb1p[threadIdx.x] = pb1[threadIdx.x]; cb2p[threadIdx.x] = pb2[threadIdx.x];
  }
  __syncthreads();

  const int lane = threadIdx.x & 63;
  const int wv   = threadIdx.x >> 6;
  const int n15  = lane & 15;
  const int quad = lane >> 4;
  const int gw = blockIdx.x * 4 + wv;
  ushort_t* hm = &hmat[wv][0];

  for (int base = gw * 64; base < E; base += gridDim.x * 256) {
    int r_lane;
    {
      int e = base + lane, ec = min(e, E - 1);
      const float4* rp = erec + ec;
      int2 sr = *(const int2*)rp;
      float dd = *((const float*)rp + 2);
      srow[wv][lane] = sr.x; rrow[wv][lane] = sr.y;
      r_lane = sr.y;
      ddv[wv][lane] = dd;
    }
    // segment-start mask for this 64-edge tile (one ballot; reused by both phases)
    unsigned long long bmask;
    {
      int rp = __shfl_up(r_lane, 1);
      bmask = __ballot((lane == 0) || (r_lane != rp));
    }
    int sm[4], rm[4];
#pragma unroll
    for (int mt = 0; mt < 4; ++mt) {
      sm[mt] = srow[wv][mt * 16 + n15];
      rm[mt] = rrow[wv][mt * 16 + n15];
    }

    // ===== fused layer-1 K-loop: acc (msg, K=257) and accp (pos, K=129) =====
    floatx4 acc[4][4], accp[4][4];
#pragma unroll
    for (int mt = 0; mt < 4; ++mt)
#pragma unroll
      for (int reg = 0; reg < 4; ++reg) {
        float dd = ddv[wv][mt * 16 + quad * 4 + reg];
#pragma unroll
        for (int nt = 0; nt < 4; ++nt) {
          acc[mt][nt][reg]  = cb1m[nt * 16 + n15] + dd * wdm[nt * 16 + n15];
          accp[mt][nt][reg] = cb1p[nt * 16 + n15] + dd * wdp[nt * 16 + n15];
        }
      }

#pragma unroll
    for (int ks = 0; ks < 8; ++ks) {
      const int seg = ks >> 1, half = ks & 1;
      const ushort_t* sb = (seg == 0 || seg == 2) ? xb : peb;
      const bool dopos = (seg & 1);              // segs 1 (pe_s) and 3 (pe_r) feed accp too
      const int  kp    = ((seg >> 1) << 1) | half;  // pos K-step index 0..3
      short8 B[4], Bp[4];
#pragma unroll
      for (int nt = 0; nt < 4; ++nt)
        B[nt] = *(const short8*)&w1m[((ks * 4 + quad) * 64 + nt * 16 + n15) * 8];
      if (dopos) {
#pragma unroll
        for (int nt = 0; nt < 4; ++nt)
          Bp[nt] = *(const short8*)&w1p[((kp * 4 + quad) * 64 + nt * 16 + n15) * 8];
      }
#pragma unroll
      for (int mt = 0; mt < 4; ++mt) {
        int row = (seg < 2) ? sm[mt] : rm[mt];
        short8 A = *(const short8*)(sb + (size_t)row * 64 + half * 32 + quad * 8);
#pragma unroll
        for (int nt = 0; nt < 4; ++nt)
          acc[mt][nt] = MFMA16(A, B[nt], acc[mt][nt]);
        if (dopos) {
#pragma unroll
          for (int nt = 0; nt < 4; ++nt)
            accp[mt][nt] = MFMA16(A, Bp[nt], accp[mt][nt]);
        }
      }
    }

    // ================= message epilogue (silu) =================
    {
      int pendR = -1; float pendV = 0.0f;
#pragma unroll
      for (int mt = 0; mt < 4; ++mt) {
#pragma unroll
        for (int nt = 0; nt < 4; ++nt) {
          const int col = nt * 16 + n15;
          unsigned p01 = cvtpk_bf16(silu1(acc[mt][nt][0]), silu1(acc[mt][nt][1]));
          unsigned p23 = cvtpk_bf16(silu1(acc[mt][nt][2]), silu1(acc[mt][nt][3]));
          hm[(quad * 4 + 0) * 72 + col] = (ushort_t)(p01 & 0xFFFFu);
          hm[(quad * 4 + 1) * 72 + col] = (ushort_t)(p01 >> 16);
          hm[(quad * 4 + 2) * 72 + col] = (ushort_t)(p23 & 0xFFFFu);
          hm[(quad * 4 + 3) * 72 + col] = (ushort_t)(p23 >> 16);
        }

        floatx4 o[4];
#pragma unroll
        for (int nt = 0; nt < 4; ++nt) {
          float bv = cb2m[nt * 16 + n15];
#pragma unroll
          for (int reg = 0; reg < 4; ++reg) o[nt][reg] = bv;
        }
#pragma unroll
        for (int ks = 0; ks < 2; ++ks) {
          short8 A = *(const short8*)&hm[n15 * 72 + ks * 32 + quad * 8];
          short8 B[4];
#pragma unroll
          for (int nt = 0; nt < 4; ++nt)
            B[nt] = *(const short8*)&w2m[((ks * 4 + quad) * 64 + nt * 16 + n15) * 8];
#pragma unroll
          for (int nt = 0; nt < 4; ++nt)
            o[nt] = MFMA16(A, B[nt], o[nt]);
        }

#pragma unroll
        for (int nt = 0; nt < 4; ++nt)
#pragma unroll
          for (int reg = 0; reg < 4; ++reg)
            o[nt][reg] = silu1(o[nt][reg]);

        // segmented reduction: register bit-walk over ballot mask (no LDS chain)
        int rem = E - (base + mt * 16);
        unsigned vmask = rem >= 16 ? 0xFFFFu : (rem <= 0 ? 0u : ((1u << rem) - 1u));
        unsigned m16 = ((unsigned)(bmask >> (mt * 16)) & 0xFFFFu) | 1u;
        int e0 = 0;
        while (e0 < 16) {
          unsigned above = m16 & ~((1u << (e0 + 1)) - 1u);
          int e1 = above ? __builtin_ctz(above) : 16;
          unsigned segm = (((e1 == 16) ? 0xFFFFu : ((1u << e1) - 1u)) & ~((1u << e0) - 1u)) & vmask;
          if (segm) {
            const int r0 = rrow[wv][mt * 16 + e0];
            float s0 = 0.0f, s1 = 0.0f, s2 = 0.0f, s3 = 0.0f;
#pragma unroll
            for (int reg = 0; reg < 4; ++reg) {
              float msk = (float)((segm >> (quad * 4 + reg)) & 1u);
              s0 = fmaf(msk, o[0][reg], s0);
              s1 = fmaf(msk, o[1][reg], s1);
              s2 = fmaf(msk, o[2][reg], s2);
              s3 = fmaf(msk, o[3][reg], s3);
            }
            s0 += __shfl_xor(s0, 16); s0 += __shfl_xor(s0, 32);
            s1 += __shfl_xor(s1, 16); s1 += __shfl_xor(s1, 32);
            s2 += __shfl_xor(s2, 16); s2 += __shfl_xor(s2, 32);
            s3 += __shfl_xor(s3, 16); s3 += __shfl_xor(s3, 32);
            float v = (quad & 2) ? ((quad & 1) ? s3 : s2) : ((quad & 1) ? s1 : s0);
            if (r0 != pendR) {
              if (pendR >= 0) unsafeAtomicAdd(aggr + (size_t)pendR * 64 + lane, pendV);
              pendR = r0; pendV = v;
            } else {
              pendV += v;
            }
          }
          e0 = e1;
        }
      }
      if (pendR >= 0) unsafeAtomicAdd(aggr + (size_t)pendR * 64 + lane, pendV);
    }

    // ================= positional epilogue (tanh) — layer-1 already in accp =================
    {
      int pendR = -1; float pendV = 0.0f;
#pragma unroll
      for (int mt = 0; mt < 4; ++mt) {
#pragma unroll
        for (int nt = 0; nt < 4; ++nt) {
          const int col = nt * 16 + n15;
          unsigned p01 = cvtpk_bf16(tanh1(accp[mt][nt][0]), tanh1(accp[mt][nt][1]));
          unsigned p23 = cvtpk_bf16(tanh1(accp[mt][nt][2]), tanh1(accp[mt][nt][3]));
          hm[(quad * 4 + 0) * 72 + col] = (ushort_t)(p01 & 0xFFFFu);
          hm[(quad * 4 + 1) * 72 + col] = (ushort_t)(p01 >> 16);
          hm[(quad * 4 + 2) * 72 + col] = (ushort_t)(p23 & 0xFFFFu);
          hm[(quad * 4 + 3) * 72 + col] = (ushort_t)(p23 >> 16);
        }

        floatx4 o[4];
#pragma unroll
        for (int nt = 0; nt < 4; ++nt) {
          float bv = cb2p[nt * 16 + n15];
#pragma unroll
          for (int reg = 0; reg < 4; ++reg) o[nt][reg] = bv;
        }
#pragma unroll
        for (int ks = 0; ks < 2; ++ks) {
          short8 A = *(const short8*)&hm[n15 * 72 + ks * 32 + quad * 8];
          short8 B[4];
#pragma unroll
          for (int nt = 0; nt < 4; ++nt)
            B[nt] = *(const short8*)&w2p[((ks * 4 + quad) * 64 + nt * 16 + n15) * 8];
#pragma unroll
          for (int nt = 0; nt < 4; ++nt)
            o[nt] = MFMA16(A, B[nt], o[nt]);
        }

#pragma unroll
        for (int nt = 0; nt < 4; ++nt)
#pragma unroll
          for (int reg = 0; reg < 4; ++reg)
            o[nt][reg] = tanh1(o[nt][reg]);

        int rem = E - (base + mt * 16);
        unsigned vmask = rem >= 16 ? 0xFFFFu : (rem <= 0 ? 0u : ((1u << rem) - 1u));
        unsigned m16 = ((unsigned)(bmask >> (mt * 16)) & 0xFFFFu) | 1u;
        int e0 = 0;
        while (e0 < 16) {
          unsigned above = m16 & ~((1u << (e0 + 1)) - 1u);
          int e1 = above ? __builtin_ctz(above) : 16;
          unsigned segm = (((e1 == 16) ? 0xFFFFu : ((1u << e1) - 1u)) & ~((1u << e0) - 1u)) & vmask;
          if (segm) {
            const int r0 = rrow[wv][mt * 16 + e0];
            float s0 = 0.0f, s1 = 0.0f, s2 = 0.0f, s3 = 0.0f;
#pragma unroll
            for (int reg = 0; reg < 4; ++reg) {
              float msk = (float)((segm >> (quad * 4 + reg)) & 1u);
              s0 = fmaf(msk, o[0][reg], s0);
              s1 = fmaf(msk, o[1][reg], s1);
              s2 = fmaf(msk, o[2][reg], s2);
              s3 = fmaf(msk, o[3][reg], s3);
            }
            s0 += __shfl_xor(s0, 16); s0 += __shfl_xor(s0, 32);
            s1 += __shfl_xor(s1, 16); s1 += __shfl_xor(s1, 32);
            s2 += __shfl_xor(s2, 16); s2 += __shfl_xor(s2, 32);
            s3 += __shfl_xor(s3, 16); s3 += __shfl_xor(s3, 32);
            float v = (quad & 2) ? ((quad & 1) ? s3 : s2) : ((quad & 1) ? s1 : s0);
            if (r0 != pendR) {
              if (pendR >= 0) unsafeAtomicAdd(aggrp + (size_t)pendR * 64 + lane, pendV);
              pendR = r0; pendV = v;
            } else {
              pendV += v;
            }
          }
          e0 = e1;
        }
      }
      if (pendR >= 0) unsafeAtomicAdd(aggrp + (size_t)pendR * 64 + lane, pendV);
    }
  }
}

// ================= merged node kernel: blocks [0,nupd) do update MLP, rest do pe MLP =================
__global__ __launch_bounds__(256, 2) void knode(
    const ushort_t* __restrict__ xb, const ushort_t* __restrict__ peb,
    const float* aggr, const float* aggrp,
    const float* __restrict__ uw1, const float* __restrict__ ub1,
    const float* __restrict__ uw2, const float* __restrict__ ub2,
    const float* __restrict__ ew1, const float* __restrict__ eb1,
    const float* __restrict__ ew2, const float* __restrict__ eb2,
    float* out_upd, float* out_upe, int N, int nupd) {
  __shared__ ushort_t shraw[34816];        // 69.6 KB union: w1b | w2b | hmat
  __shared__ float cb1[64], cb2[64];

  const bool isupd = ((int)blockIdx.x < nupd);
  const int  K1    = isupd ? 192 : 128;
  ushort_t* w1b  = shraw;
  ushort_t* w2b  = shraw + (isupd ? 12288 : 8192);
  ushort_t* hmat = shraw + (isupd ? 16384 : 12288);  // 4 waves x 4608 ushort
  const float* w1 = isupd ? uw1 : ew1;
  const float* b1 = isupd ? ub1 : eb1;
  const float* w2 = isupd ? uw2 : ew2;
  const float* b2 = isupd ? ub2 : eb2;
  const float* ag = isupd ? aggr : aggrp;
  float* outp     = isupd ? out_upd : out_upe;

  for (int i = threadIdx.x * 4; i < K1 * 64; i += 1024) {
    float4 w = *(const float4*)&w1[i];
    int k = i >> 6, n = i & 63;
    int off = (((k >> 5) * 4 + ((k >> 3) & 3)) * 64 + n) * 8 + (k & 7);
    w1b[off] = f2bf(w.x); w1b[off + 8] = f2bf(w.y);
    w1b[off + 16] = f2bf(w.z); w1b[off + 24] = f2bf(w.w);
  }
  for (int i = threadIdx.x * 4; i < 64 * 64; i += 1024) {
    float4 w = *(const float4*)&w2[i];
    int k = i >> 6, n = i & 63;
    int off = (((k >> 5) * 4 + ((k >> 3) & 3)) * 64 + n) * 8 + (k & 7);
    w2b[off] = f2bf(w.x); w2b[off + 8] = f2bf(w.y);
    w2b[off + 16] = f2bf(w.z); w2b[off + 24] = f2bf(w.w);
  }
  if (threadIdx.x < 64) { cb1[threadIdx.x] = b1[threadIdx.x]; cb2[threadIdx.x] = b2[threadIdx.x]; }
  __syncthreads();

  const int lane = threadIdx.x & 63;
  const int wv   = threadIdx.x >> 6;
  const int n15  = lane & 15;
  const int quad = lane >> 4;
  const int bid  = isupd ? (int)blockIdx.x : ((int)blockIdx.x - nupd);
  const int nblk = isupd ? nupd : (gridDim.x - nupd);
  const int gw   = bid * 4 + wv;
  ushort_t* hm = hmat + wv * 4608;

  for (int base = gw * 64; base < N; base += nblk * 256) {
    floatx4 acc[4][4];
#pragma unroll
    for (int mt = 0; mt < 4; ++mt)
#pragma unroll
      for (int nt = 0; nt < 4; ++nt) {
        float bv = cb1[nt * 16 + n15];
#pragma unroll
        for (int reg = 0; reg < 4; ++reg) acc[mt][nt][reg] = bv;
      }

    // layer 1: K1 in steps of 32.
    const int nks = K1 >> 5;
    for (int ks = 0; ks < nks; ++ks) {
      const int seg = ks >> 1, half = ks & 1;
      const int lastseg = (nks >> 1) - 1;
      short8 B[4];
#pragma unroll
      for (int nt = 0; nt < 4; ++nt)
        B[nt] = *(const short8*)&w1b[((ks * 4 + quad) * 64 + nt * 16 + n15) * 8];
#pragma unroll
      for (int mt = 0; mt < 4; ++mt) {
        int row = min(base + mt * 16 + n15, N - 1);
        short8 A;
        if (seg == lastseg) {          // aggregated messages, fp32 -> bf16
          const float* ap = ag + (size_t)row * 64 + half * 32 + quad * 8;
          float4 f0 = *(const float4*)ap;
          float4 f1 = *(const float4*)(ap + 4);
          union { ushort_t u[8]; short8 s; } pk;
          pk.u[0] = f2bf(f0.x); pk.u[1] = f2bf(f0.y); pk.u[2] = f2bf(f0.z); pk.u[3] = f2bf(f0.w);
          pk.u[4] = f2bf(f1.x); pk.u[5] = f2bf(f1.y); pk.u[6] = f2bf(f1.z); pk.u[7] = f2bf(f1.w);
          A = pk.s;
        } else if (seg == 0 && isupd) {
          A = *(const short8*)(xb + (size_t)row * 64 + half * 32 + quad * 8);
        } else {
          A = *(const short8*)(peb + (size_t)row * 64 + half * 32 + quad * 8);
        }
#pragma unroll
        for (int nt = 0; nt < 4; ++nt)
          acc[mt][nt] = MFMA16(A, B[nt], acc[mt][nt]);
      }
    }

    // epilogue 1: act -> bf16 h-matrix (full 64x72)
#pragma unroll
    for (int mt = 0; mt < 4; ++mt)
#pragma unroll
      for (int nt = 0; nt < 4; ++nt)
#pragma unroll
        for (int reg = 0; reg < 4; ++reg) {
          float h = isupd ? silu1(acc[mt][nt][reg]) : tanh1(acc[mt][nt][reg]);
          hm[(mt * 16 + quad * 4 + reg) * 72 + nt * 16 + n15] = f2bf(h);
        }

    // layer 2: K=64 in 2 steps
    floatx4 o[4][4];
#pragma unroll
    for (int mt = 0; mt < 4; ++mt)
#pragma unroll
      for (int nt = 0; nt < 4; ++nt) {
        float bv = cb2[nt * 16 + n15];
#pragma unroll
        for (int reg = 0; reg < 4; ++reg) o[mt][nt][reg] = bv;
      }
#pragma unroll
    for (int ks = 0; ks < 2; ++ks) {
      short8 B[4];
#pragma unroll
      for (int nt = 0; nt < 4; ++nt)
        B[nt] = *(const short8*)&w2b[((ks * 4 + quad) * 64 + nt * 16 + n15) * 8];
#pragma unroll
      for (int mt = 0; mt < 4; ++mt) {
        short8 A = *(const short8*)&hm[(mt * 16 + n15) * 72 + ks * 32 + quad * 8];
#pragma unroll
        for (int nt = 0; nt < 4; ++nt)
          o[mt][nt] = MFMA16(A, B[nt], o[mt][nt]);
      }
    }

#pragma unroll
    for (int mt = 0; mt < 4; ++mt)
#pragma unroll
      for (int reg = 0; reg < 4; ++reg) {
        const int row = base + mt * 16 + quad * 4 + reg;
        if (row < N) {
#pragma unroll
          for (int nt = 0; nt < 4; ++nt) {
            float v = o[mt][nt][reg];
            outp[(size_t)row * 64 + nt * 16 + n15] = isupd ? v : tanh1(v);
          }
        }
      }
  }
}

extern "C" void kernel_launch(void* const* d_in, const int* in_sizes, int n_in,
                              void* d_out, int out_size, void* d_ws, size_t ws_size,
                              hipStream_t stream) {
  const float* x    = (const float*)d_in[0];
  const float* pos  = (const float*)d_in[1];
  const float* pe   = (const float*)d_in[2];
  const int*   eidx = (const int*)d_in[3];
  const float* msg_w1  = (const float*)d_in[4];
  const float* msg_b1  = (const float*)d_in[5];
  const float* msg_w2  = (const float*)d_in[6];
  const float* msg_b2  = (const float*)d_in[7];
  const float* mpos_w1 = (const float*)d_in[8];
  const float* mpos_b1 = (const float*)d_in[9];
  const float* mpos_w2 = (const float*)d_in[10];
  const float* mpos_b2 = (const float*)d_in[11];
  const float* upd_w1  = (const float*)d_in[12];
  const float* upd_b1  = (const float*)d_in[13];
  const float* upd_w2  = (const float*)d_in[14];
  const float* upd_b2  = (const float*)d_in[15];
  const float* upe_w1  = (const float*)d_in[16];
  const float* upe_b1  = (const float*)d_in[17];
  const float* upe_w2  = (const float*)d_in[18];
  const float* upe_b2  = (const float*)d_in[19];

  const int N = in_sizes[0] / HDIM;
  const int E = in_sizes[3] / 2;

  float* out_upd = (float*)d_out;                 // aggr accumulator, then update out
  float* out_upe = out_upd + (size_t)N * HDIM;    // aggr_pos accumulator, then update_pe out

  // workspace layout: xb | peb | cnt[N] pad[4] | erec[E] (16B-aligned) | part | erank
  ushort_t* xb    = (ushort_t*)d_ws;
  ushort_t* peb   = xb + (size_t)N * HDIM;
  int*      cnt   = (int*)(peb + (size_t)N * HDIM);
  int*      pad4  = cnt + N;
  float4*   erec  = (float4*)(pad4 + 4);
  int*      part  = (int*)(erec + E);
  int*      erank = part + 1024;

  hipMemsetAsync(d_out, 0, (size_t)2 * N * HDIM * sizeof(float), stream);
  hipMemsetAsync(cnt, 0, (size_t)N * sizeof(int), stream);

  const int ncv = N * HDIM;
  const int ncvtblk = (2 * ncv / 8 + 255) / 256;
  const int nhist = 2048;
  kprep<<<ncvtblk + nhist, 256, 0, stream>>>(x, pe, xb, ncv, eidx, cnt, erank, E,
                                             ncvtblk, nhist);

  const int nb = (N + 255) / 256;
  kscanA<<<nb, 256, 0, stream>>>(cnt, part, N);
  kscanB<<<1, 1024, 0, stream>>>(part, nb);
  kscanC<<<nb, 256, 0, stream>>>(cnt, part, N);
  kscatter<<<2048, 256, 0, stream>>>(eidx, cnt, erank, pos, erec, E);

  kedge<<<512, 256, 0, stream>>>(xb, peb, erec,
                                 msg_w1, msg_b1, msg_w2, msg_b2,
                                 mpos_w1, mpos_b1, mpos_w2, mpos_b2,
                                 out_upd, out_upe, E);

  // merged node kernel: both MLPs in one dispatch
  const int ntiles = (N + 63) / 64;
  const int nupd   = (ntiles + 3) / 4;
  knode<<<2 * nupd, 256, 0, stream>>>(xb, peb, out_upd, out_upe,
                                      upd_w1, upd_b1, upd_w2, upd_b2,
                                      upe_w1, upe_b1, upe_w2, upe_b2,
                                      out_upd, out_upe, N, nupd);
}